// Round 10
// baseline (564.211 us; speedup 1.0000x reference)
//
#include <hip/hip_runtime.h>

#define BB 128
#define TE 2048
#define UU 256
#define IN_DIM 256
#define MC 32   // rows per chunk
#define NCH 8   // chunks per block
#define GPB 8   // blocks per batch row (TE / (MC*NCH))

typedef float f32x4 __attribute__((ext_vector_type(4)));
typedef __fp16 f16x2 __attribute__((ext_vector_type(2)));   // matches cvt_pkrtz return type
typedef _Float16 f16x8 __attribute__((ext_vector_type(8)));

__device__ __forceinline__ float fast_tanh(float x) {
  float e = __expf(2.f * x);
  return 1.f - 2.f / (e + 1.f);
}
__device__ __forceinline__ float fast_sigmoid(float x) {
  return 1.f / (1.f + __expf(-x));
}
// LDS-only barrier: drains ds ops, does NOT drain vmcnt (keeps global prefetch in flight)
__device__ __forceinline__ void bar_lds() {
  asm volatile("s_waitcnt lgkmcnt(0)" ::: "memory");
  __builtin_amdgcn_s_barrier();
}

// ---- prep: addvec = h_tm@W_a + b_a (blocks 0..127); UhT2 = f16 frag-major U_a (blocks 128..159)
// UhT2 layout: [k0/8][n][8] i.e. frag (ks,lg) for MFMA B: 16B at ((ks*4+lg)*256 + n)*8 halves
__global__ __launch_bounds__(256) void prep_kernel(
    const float* __restrict__ h_tm, const float* __restrict__ W_a,
    const float* __restrict__ b_a, const float* __restrict__ U_a,
    float* __restrict__ addvec, _Float16* __restrict__ UhT2) {
  int t = threadIdx.x;
  if (blockIdx.x < BB) {
    int bi = blockIdx.x;
    __shared__ float hL[UU];
    hL[t] = h_tm[bi * UU + t];
    __syncthreads();
    float s = b_a[t];
    for (int e = 0; e < UU; ++e) s += hL[e] * W_a[e * UU + t];
    addvec[bi * UU + t] = s;
  } else {
    int b2 = blockIdx.x - BB;  // 0..31 -> k0 = b2*8
    int n = t;
    union { f16x8 v; _Float16 h[8]; } pk;
#pragma unroll
    for (int e = 0; e < 8; ++e) pk.h[e] = (_Float16)U_a[(b2 * 8 + e) * UU + n];
    *(f16x8*)(UhT2 + ((b2 * UU + n) << 3)) = pk.v;
  }
}

// ---- main: block = (batch bi, group g of 256 timesteps); 8 chunks of 32 rows,
// double-buffered fp32 LDS tile, async-stage split, B-frags resident in VGPRs.
__global__ __launch_bounds__(256, 2) void attn_main(
    const float* __restrict__ x_seq, const float* __restrict__ V_a,
    const _Float16* __restrict__ UhT2, const float* __restrict__ addvec,
    float* __restrict__ numw, float* __restrict__ denw) {
  __shared__ __align__(16) float Xb[2][MC * UU];  // 2 x 32 KB, 16B-unit XOR swizzle u^=(row&7)
  __shared__ float avL[UU], vaL[UU];
  __shared__ float wsum[4][MC];
  __shared__ float eL[MC];

  const int tid = threadIdx.x;
  const int bi = blockIdx.x >> 3;
  const int g = blockIdx.x & 7;
  const float* xc = x_seq + (size_t)(bi * TE + g * (MC * NCH)) * UU;

  const int w = tid >> 6, l = tid & 63, lr = l & 15, lg = l >> 4;
  const int rlow = lr & 7;

  // issue chunk-0 global loads (held in regs)
  f32x4 st[8];
#pragma unroll
  for (int j = 0; j < 8; ++j) st[j] = *(const f32x4*)(xc + (size_t)(j * 256 + tid) * 4);

  avL[tid] = addvec[bi * UU + tid];
  vaL[tid] = V_a[tid];

  // B fragments resident: Bf[ks][ni], lane(lr,lg) holds B[k=ks*32+lg*8..+7][n=w*64+ni*16+lr]
  f16x8 Bf[8][4];
#pragma unroll
  for (int ks = 0; ks < 8; ++ks)
#pragma unroll
    for (int ni = 0; ni < 4; ++ni) {
      int n = w * 64 + ni * 16 + lr;
      Bf[ks][ni] = *(const f16x8*)(UhT2 + (((ks * 4 + lg) * UU + n) << 3));
    }

  // write chunk0 -> buf0 (swizzled), then issue chunk1
  {
    float* B0 = &Xb[0][0];
#pragma unroll
    for (int j = 0; j < 8; ++j) {
      int row = j * 4 + (tid >> 6), u = tid & 63;
      *(f32x4*)(B0 + (((row << 6) + (u ^ (row & 7))) << 2)) = st[j];
    }
  }
#pragma unroll
  for (int j = 0; j < 8; ++j)
    st[j] = *(const f32x4*)(xc + (size_t)(MC * UU) + (size_t)(j * 256 + tid) * 4);
  bar_lds();

  float num_acc = 0.f, den_acc = 0.f;
  for (int i = 0; i < NCH; ++i) {
    const float* Xc = &Xb[i & 1][0];
    f32x4 acc[2][4];
#pragma unroll
    for (int mi = 0; mi < 2; ++mi)
#pragma unroll
      for (int ni = 0; ni < 4; ++ni) acc[mi][ni] = (f32x4)0.f;

#pragma unroll
    for (int ks = 0; ks < 8; ++ks) {
      f16x8 a[2];
#pragma unroll
      for (int mi = 0; mi < 2; ++mi) {
        const int rowoff = (mi * 16 + lr) << 8;
        int u0 = ks * 8 + lg * 2;
        f32x4 f0 = *(const f32x4*)(Xc + rowoff + ((u0 ^ rlow) << 2));
        f32x4 f1 = *(const f32x4*)(Xc + rowoff + (((u0 + 1) ^ rlow) << 2));
        union { f16x8 v; f16x2 p[4]; } A;
        A.p[0] = __builtin_amdgcn_cvt_pkrtz(f0.x, f0.y);
        A.p[1] = __builtin_amdgcn_cvt_pkrtz(f0.z, f0.w);
        A.p[2] = __builtin_amdgcn_cvt_pkrtz(f1.x, f1.y);
        A.p[3] = __builtin_amdgcn_cvt_pkrtz(f1.z, f1.w);
        a[mi] = A.v;
      }
#pragma unroll
      for (int mi = 0; mi < 2; ++mi)
#pragma unroll
        for (int ni = 0; ni < 4; ++ni)
          acc[mi][ni] = __builtin_amdgcn_mfma_f32_16x16x32_f16(a[mi], Bf[ks][ni],
                                                               acc[mi][ni], 0, 0, 0);
    }

    // epilogue: et rows for this chunk
    float psum[2][4];
#pragma unroll
    for (int mi = 0; mi < 2; ++mi)
#pragma unroll
      for (int r = 0; r < 4; ++r) psum[mi][r] = 0.f;
#pragma unroll
    for (int ni = 0; ni < 4; ++ni) {
      int n = w * 64 + ni * 16 + lr;
      float av = avL[n], va = vaL[n];
#pragma unroll
      for (int mi = 0; mi < 2; ++mi)
#pragma unroll
        for (int r = 0; r < 4; ++r)
          psum[mi][r] += fast_tanh(acc[mi][ni][r] + av) * va;
    }
#pragma unroll
    for (int off = 1; off < 16; off <<= 1)
#pragma unroll
      for (int mi = 0; mi < 2; ++mi)
#pragma unroll
        for (int r = 0; r < 4; ++r) psum[mi][r] += __shfl_xor(psum[mi][r], off, 64);
    if (lr == 0) {
#pragma unroll
      for (int mi = 0; mi < 2; ++mi)
#pragma unroll
        for (int r = 0; r < 4; ++r) wsum[w][mi * 16 + lg * 4 + r] = psum[mi][r];
    }
    bar_lds();
    if (tid < MC) {
      float et = wsum[0][tid] + wsum[1][tid] + wsum[2][tid] + wsum[3][tid];
      eL[tid] = __expf(et);  // unnormalized, matches reference
    }
    bar_lds();

    // num/den accumulation (reads exact fp32 X from LDS; eL broadcast)
#pragma unroll 8
    for (int m = 0; m < MC; ++m) {
      float e = eL[m];
      num_acc += e * Xc[(m << 8) + ((((tid >> 2) ^ (m & 7))) << 2) + (tid & 3)];
      den_acc += e;
    }

    if (i < NCH - 1) {
      float* Bn = &Xb[(i + 1) & 1][0];
#pragma unroll
      for (int j = 0; j < 8; ++j) {
        int row = j * 4 + (tid >> 6), u = tid & 63;
        *(f32x4*)(Bn + (((row << 6) + (u ^ (row & 7))) << 2)) = st[j];
      }
      if (i < NCH - 2) {
        const float* src = xc + (size_t)(i + 2) * (MC * UU);
#pragma unroll
        for (int j = 0; j < 8; ++j) st[j] = *(const f32x4*)(src + (size_t)(j * 256 + tid) * 4);
      }
      bar_lds();
    }
  }
  numw[(bi * GPB + g) * UU + tid] = num_acc;
  if (tid == 0) denw[bi * GPB + g] = den_acc;
}

// ---- finalize: 1024 threads, gate matvecs e-split 4-way with LDS partials
__global__ __launch_bounds__(1024) void finalize_kernel(
    const float* __restrict__ inputs, const float* __restrict__ h_tm,
    const float* __restrict__ numw, const float* __restrict__ denw,
    const float* __restrict__ C_z, const float* __restrict__ W_z,
    const float* __restrict__ b_z, const float* __restrict__ C_r,
    const float* __restrict__ W_r, const float* __restrict__ b_r,
    const float* __restrict__ C_p, const float* __restrict__ U_p,
    const float* __restrict__ b_p, float* __restrict__ out) {
  int bi = blockIdx.x, tid = threadIdx.x;
  int t = tid & 255, s = tid >> 8;  // output col, e-slice
  __shared__ float hL[UU], ciL[IN_DIM + UU], rhL[UU];
  __shared__ float zp[4][UU], rp[4][UU], pp[4][UU];

  if (s == 0) {
    float ns = 0.f;
#pragma unroll
    for (int c = 0; c < GPB; ++c) ns += numw[(bi * GPB + c) * UU + t];
    float ds = 0.f;
#pragma unroll
    for (int c = 0; c < GPB; ++c) ds += denw[bi * GPB + c];
    ciL[IN_DIM + t] = ns / ds;         // context
    ciL[t] = inputs[bi * IN_DIM + t];  // inputs
    hL[t] = h_tm[bi * UU + t];
  }
  __syncthreads();

  float z = 0.f, r = 0.f, p = 0.f;
  for (int e = s * 64; e < s * 64 + 64; ++e) {
    float h = hL[e];
    z += h * W_z[e * UU + t];
    r += h * W_r[e * UU + t];
  }
  for (int e = s * 128; e < s * 128 + 128; ++e) {
    float cv = ciL[e];
    z += cv * C_z[e * UU + t];
    r += cv * C_r[e * UU + t];
    p += cv * C_p[e * UU + t];
  }
  zp[s][t] = z; rp[s][t] = r; pp[s][t] = p;
  __syncthreads();

  if (s == 0) {
    float zz = zp[0][t] + zp[1][t] + zp[2][t] + zp[3][t] + b_z[t];
    float rr = rp[0][t] + rp[1][t] + rp[2][t] + rp[3][t] + b_r[t];
    zz = fast_sigmoid(zz);
    rr = fast_sigmoid(rr);
    zp[0][t] = zz;          // stash final z
    rhL[t] = rr * hL[t];
  }
  __syncthreads();

  float p2 = 0.f;
  for (int e = s * 64; e < s * 64 + 64; ++e) p2 += rhL[e] * U_p[e * UU + t];
  pp[s][t] += p2;
  __syncthreads();

  if (s == 0) {
    float pt = pp[0][t] + pp[1][t] + pp[2][t] + pp[3][t] + b_p[t];
    float th = fast_tanh(pt);
    float zz = zp[0][t];
    out[bi * UU + t] = (1.f - zz) * hL[t] + zz * th;
  }
}

extern "C" void kernel_launch(void* const* d_in, const int* in_sizes, int n_in,
                              void* d_out, int out_size, void* d_ws, size_t ws_size,
                              hipStream_t stream) {
  const float* inputs = (const float*)d_in[0];
  const float* h_tm = (const float*)d_in[1];
  const float* x_seq = (const float*)d_in[2];
  const float* V_a = (const float*)d_in[3];
  const float* W_a = (const float*)d_in[4];
  const float* U_a = (const float*)d_in[5];
  const float* b_a = (const float*)d_in[6];
  const float* C_z = (const float*)d_in[7];
  const float* W_z = (const float*)d_in[8];
  const float* b_z = (const float*)d_in[9];
  const float* C_r = (const float*)d_in[10];
  const float* W_r = (const float*)d_in[11];
  const float* b_r = (const float*)d_in[12];
  const float* C_p = (const float*)d_in[13];
  const float* U_p = (const float*)d_in[14];
  const float* b_p = (const float*)d_in[15];

  // ws: UhT2 f16 [32][256][8] (128KB) | addvec f32 (128KB) | numw f32 [128][8][256] (1MB) | denw [128][8]
  _Float16* UhT2 = (_Float16*)d_ws;
  float* addvec = (float*)((char*)d_ws + 131072);
  float* numw = (float*)((char*)d_ws + 262144);
  float* denw = (float*)((char*)d_ws + 262144 + 1048576);
  float* out = (float*)d_out;

  prep_kernel<<<BB + 32, 256, 0, stream>>>(h_tm, W_a, b_a, U_a, addvec, UhT2);
  attn_main<<<BB * GPB, 256, 0, stream>>>(x_seq, V_a, UhT2, addvec, numw, denw);
  finalize_kernel<<<BB, 1024, 0, stream>>>(inputs, h_tm, numw, denw, C_z, W_z, b_z,
                                           C_r, W_r, b_r, C_p, U_p, b_p, out);
}